// Round 3
// baseline (65.611 us; speedup 1.0000x reference)
//
#include <hip/hip_runtime.h>

// Fused attention block: B=4, S=2048, F=512, D=64
//  q = x@Wq + bq ; k = x@Wk + bk ; v = x@Wv + bv      (B,S,D)
//  logits = q@k^T / 8 + (1-mask)*-1e9 ; attn = softmax ; out = attn@v
//
// All GEMMs via v_mfma_f32_16x16x32_bf16 (f32 accumulate).
// Fragment layouts (guide §3, m89/m91-verified):
//   A: lane holds A[row = lane&15][k = (lane>>4)*8 + e], e=0..7
//   B: lane holds B[k = (lane>>4)*8 + e][col = lane&15]
//   C/D: lane holds D[row = (lane>>4)*4 + r][col = lane&15], r=0..3
//
// R3: attn processes 64 keys/iter (half the serial softmax-reduce rounds);
// proj splits F across 2 waves/block (3 waves/SIMD TLP) + LDS combine.

typedef __attribute__((ext_vector_type(8))) short bhalf8;
typedef __attribute__((ext_vector_type(4))) float fx4;

#define MFMA(a, b, c) __builtin_amdgcn_mfma_f32_16x16x32_bf16((a), (b), (c), 0, 0, 0)

__device__ __forceinline__ short f2bf(float f) {
    union { float f; unsigned u; } v; v.f = f;
    unsigned r = (v.u + 0x7FFFu + ((v.u >> 16) & 1u)) >> 16;  // RNE
    return (short)r;
}

// ---- Kernel 1: W (512x64 f32, row-major [F][D]) -> Wt[3][64][512] bf16 (transposed) ----
__global__ void wt_kernel(const float* __restrict__ Wq,
                          const float* __restrict__ Wk,
                          const float* __restrict__ Wv,
                          short* __restrict__ Wt) {
    int tid = blockIdx.x * blockDim.x + threadIdx.x;   // 0 .. 3*64*512-1
    int m   = tid >> 15;                                // which matrix
    int rem = tid & 32767;
    int d   = rem >> 9;                                 // output col 0..63
    int k   = rem & 511;                                // input feature 0..511
    const float* W = (m == 0) ? Wq : (m == 1) ? Wk : Wv;
    Wt[tid] = f2bf(W[k * 64 + d]);
}

// ---- Kernel 2: QKV projection. 2 waves/block, each wave an F-half; 16 rows,
// one matrix per block; LDS partial-sum combine. grid 512*3, 128 thr ----
__global__ __launch_bounds__(128) void proj_kernel(const float* __restrict__ x,
                                                   const short* __restrict__ Wt,
                                                   const float* __restrict__ bq,
                                                   const float* __restrict__ bk,
                                                   const float* __restrict__ bv,
                                                   short* __restrict__ Qb,
                                                   short* __restrict__ Kb,
                                                   short* __restrict__ Vt) {
    const int lane = threadIdx.x & 63;
    const int w    = threadIdx.x >> 6;          // F-half 0/1
    const int g = lane >> 4, c = lane & 15;
    const int mat = blockIdx.x % 3;
    const int rt  = blockIdx.x / 3;
    const int rowbase = rt * 16;
    const float* xrow = x + (size_t)(rowbase + c) * 512 + w * 256;  // A row = lane&15
    const short* Wm = Wt + (size_t)mat * 64 * 512 + w * 256;

    fx4 acc[4];
#pragma unroll
    for (int t = 0; t < 4; ++t) acc[t] = (fx4){0.f, 0.f, 0.f, 0.f};

#pragma unroll 4
    for (int ks = 0; ks < 8; ++ks) {
        const int k0 = ks * 32 + g * 8;
        const float4 x0 = *(const float4*)(xrow + k0);
        const float4 x1 = *(const float4*)(xrow + k0 + 4);
        bhalf8 a;
        a[0] = f2bf(x0.x); a[1] = f2bf(x0.y); a[2] = f2bf(x0.z); a[3] = f2bf(x0.w);
        a[4] = f2bf(x1.x); a[5] = f2bf(x1.y); a[6] = f2bf(x1.z); a[7] = f2bf(x1.w);
#pragma unroll
        for (int t = 0; t < 4; ++t) {
            const bhalf8 bf = *(const bhalf8*)(Wm + (size_t)(t * 16 + c) * 512 + k0);
            acc[t] = MFMA(a, bf, acc[t]);
        }
    }

    __shared__ fx4 accl[4][64];
    if (w == 1) {
#pragma unroll
        for (int t = 0; t < 4; ++t) accl[t][lane] = acc[t];
    }
    __syncthreads();
    if (w == 0) {
        const float* bias = (mat == 0) ? bq : (mat == 1) ? bk : bv;
#pragma unroll
        for (int t = 0; t < 4; ++t) {
            const fx4 other = accl[t][lane];
            const int col = t * 16 + c;
            const float bv_ = bias[col];
#pragma unroll
            for (int r = 0; r < 4; ++r) {
                const int row = rowbase + g * 4 + r;      // D row = (lane>>4)*4+r
                const short hv = f2bf(acc[t][r] + other[r] + bv_);
                if (mat == 0)      Qb[row * 64 + col] = hv;
                else if (mat == 1) Kb[row * 64 + col] = hv;
                else               Vt[((size_t)(row >> 11) * 64 + col) * 2048 + (row & 2047)] = hv;
            }
        }
    }
}

// ---- Kernel 3: flash attention. 8 waves/block, 16 q-rows/block, per-wave
// 256-key slice (4 iters x 64 keys), private online softmax, LDS combine ----
__global__ __launch_bounds__(512) void attn_kernel(const short* __restrict__ Qb,
                                                   const short* __restrict__ Kb,
                                                   const short* __restrict__ Vt,
                                                   const int* __restrict__ mask,
                                                   float* __restrict__ out) {
    const int tid  = threadIdx.x;
    const int wid  = tid >> 6;
    const int lane = tid & 63;
    const int g = lane >> 4, c = lane & 15;
    const int b     = blockIdx.x >> 7;
    const int qbase = (blockIdx.x & 127) << 4;
    const short* Qp = Qb + (size_t)(b * 2048 + qbase) * 64;
    const short* Kp = Kb + (size_t)b * 2048 * 64;
    const short* Vp = Vt + (size_t)b * 64 * 2048;
    const int*   mp = mask + b * 2048;

    // Q fragments for the two d-halves (A operand of QK^T)
    const bhalf8 qf0 = *(const bhalf8*)(Qp + c * 64 + g * 8);
    const bhalf8 qf1 = *(const bhalf8*)(Qp + c * 64 + 32 + g * 8);

    float m_r[4], l_r[4];
    fx4 o[4];
#pragma unroll
    for (int r = 0; r < 4; ++r) { m_r[r] = -1e30f; l_r[r] = 0.f; }
#pragma unroll
    for (int dt = 0; dt < 4; ++dt) o[dt] = (fx4){0.f, 0.f, 0.f, 0.f};

    __shared__ float olds[8][16][65];   // per-wave partial O (pad 65: no bank clash)
    __shared__ float mlds[8][16];
    __shared__ float llds[8][16];
    __shared__ short Plds[8][16][72];   // pad 72: 16B-aligned rows, spread banks

    for (int kt = 0; kt < 4; ++kt) {
        const int kb = (wid * 4 + kt) * 64;
        // ---- QK^T: four 16-key n-tiles, K=64 over two ksteps each ----
        bhalf8 kf[4][2];
#pragma unroll
        for (int t = 0; t < 4; ++t) {
            const short* kp = Kp + (size_t)(kb + t * 16 + c) * 64 + g * 8;  // B col = key
            kf[t][0] = *(const bhalf8*)(kp);
            kf[t][1] = *(const bhalf8*)(kp + 32);
        }
        fx4 s[4];
#pragma unroll
        for (int t = 0; t < 4; ++t) {
            s[t] = (fx4){0.f, 0.f, 0.f, 0.f};
            s[t] = MFMA(qf0, kf[t][0], s[t]);
            s[t] = MFMA(qf1, kf[t][1], s[t]);
        }
        // ---- mask + scale; online softmax (rows g*4+r, cols c+16t) ----
        float madd[4];
#pragma unroll
        for (int t = 0; t < 4; ++t) madd[t] = mp[kb + t * 16 + c] ? 0.f : -1e9f;
        float p[4][4], tm[4];
#pragma unroll
        for (int r = 0; r < 4; ++r) {
            tm[r] = -1e30f;
#pragma unroll
            for (int t = 0; t < 4; ++t) {
                p[t][r] = s[t][r] * 0.125f + madd[t];
                tm[r] = fmaxf(tm[r], p[t][r]);
            }
        }
#pragma unroll
        for (int r = 0; r < 4; ++r) {   // row-max across the 16 lanes of the group
            tm[r] = fmaxf(tm[r], __shfl_xor(tm[r], 1));
            tm[r] = fmaxf(tm[r], __shfl_xor(tm[r], 2));
            tm[r] = fmaxf(tm[r], __shfl_xor(tm[r], 4));
            tm[r] = fmaxf(tm[r], __shfl_xor(tm[r], 8));
        }
        float fac[4];
#pragma unroll
        for (int r = 0; r < 4; ++r) {
            const float nm = fmaxf(m_r[r], tm[r]);
            fac[r] = __expf(m_r[r] - nm);
            m_r[r] = nm;
            float rs = 0.f;
#pragma unroll
            for (int t = 0; t < 4; ++t) {
                p[t][r] = __expf(p[t][r] - nm);
                rs += p[t][r];
            }
            rs += __shfl_xor(rs, 1);
            rs += __shfl_xor(rs, 2);
            rs += __shfl_xor(rs, 4);
            rs += __shfl_xor(rs, 8);
            l_r[r] = l_r[r] * fac[r] + rs;
        }
#pragma unroll
        for (int dt = 0; dt < 4; ++dt)
#pragma unroll
            for (int r = 0; r < 4; ++r) o[dt][r] *= fac[r];

        // ---- P -> LDS (re-fragment for PV A-operand); intra-wave only ----
        asm volatile("" ::: "memory");
#pragma unroll
        for (int t = 0; t < 4; ++t)
#pragma unroll
            for (int r = 0; r < 4; ++r)
                Plds[wid][g * 4 + r][t * 16 + c] = f2bf(p[t][r]);
        asm volatile("s_waitcnt lgkmcnt(0)" ::: "memory");
        const bhalf8 pa0 = *(const bhalf8*)(&Plds[wid][c][g * 8]);       // A row=q
        const bhalf8 pa1 = *(const bhalf8*)(&Plds[wid][c][32 + g * 8]);
#pragma unroll
        for (int dt = 0; dt < 4; ++dt) {
            const short* vp = Vp + (size_t)(dt * 16 + c) * 2048 + kb + g * 8;
            const bhalf8 vf0 = *(const bhalf8*)(vp);
            const bhalf8 vf1 = *(const bhalf8*)(vp + 32);
            o[dt] = MFMA(pa0, vf0, o[dt]);
            o[dt] = MFMA(pa1, vf1, o[dt]);
        }
    }

    // ---- publish per-wave partial state ----
    if (c == 0) {
#pragma unroll
        for (int r = 0; r < 4; ++r) {
            mlds[wid][g * 4 + r] = m_r[r];
            llds[wid][g * 4 + r] = l_r[r];
        }
    }
#pragma unroll
    for (int dt = 0; dt < 4; ++dt)
#pragma unroll
        for (int r = 0; r < 4; ++r)
            olds[wid][g * 4 + r][dt * 16 + c] = o[dt][r];
    __syncthreads();

    // ---- cross-wave combine: out = sum_w e^{m_w-M} o_w / sum_w e^{m_w-M} l_w ----
    float* op = out + (size_t)(b * 2048 + qbase) * 64;
#pragma unroll
    for (int i = 0; i < 2; ++i) {
        const int idx = tid + i * 512;        // 0..1023 over (row,d)
        const int row = idx >> 6, d = idx & 63;
        float M = mlds[0][row];
#pragma unroll
        for (int w = 1; w < 8; ++w) M = fmaxf(M, mlds[w][row]);
        float num = 0.f, den = 0.f;
#pragma unroll
        for (int w = 0; w < 8; ++w) {
            const float wt = __expf(mlds[w][row] - M);
            num += wt * olds[w][row][d];
            den += wt * llds[w][row];
        }
        op[row * 64 + d] = num / den;
    }
}

extern "C" void kernel_launch(void* const* d_in, const int* in_sizes, int n_in,
                              void* d_out, int out_size, void* d_ws, size_t ws_size,
                              hipStream_t stream) {
    const float* x    = (const float*)d_in[0];
    const int*   mask = (const int*)d_in[1];
    const float* Wq   = (const float*)d_in[2];
    const float* bq   = (const float*)d_in[3];
    const float* Wk   = (const float*)d_in[4];
    const float* bk   = (const float*)d_in[5];
    const float* Wv   = (const float*)d_in[6];
    const float* bv   = (const float*)d_in[7];
    float* out = (float*)d_out;

    short* Wt = (short*)d_ws;                 // 3*64*512
    short* Qb = Wt + 3 * 64 * 512;            // 4*2048*64
    short* Kb = Qb + 4 * 2048 * 64;           // 4*2048*64
    short* Vt = Kb + 4 * 2048 * 64;           // 4*2048*64  (transposed [B][64][2048])

    wt_kernel<<<384, 256, 0, stream>>>(Wq, Wk, Wv, Wt);
    proj_kernel<<<1536, 128, 0, stream>>>(x, Wt, bq, bk, bv, Qb, Kb, Vt);
    attn_kernel<<<512, 512, 0, stream>>>(Qb, Kb, Vt, mask, out);
}